// Round 7
// baseline (601.585 us; speedup 1.0000x reference)
//
#include <hip/hip_runtime.h>
#include <cstddef>
#include <cstdint>

// Problem: B=2, S=2048, E=1024, H=16, D=64.  Softmax over HEADS (ref quirk).
#define BATCH 2
#define S_LEN 2048
#define E_DIM 1024
#define NH    16
#define HD    64
#define M_ROWS (BATCH * S_LEN)   // 4096
#define KSPLIT 4
#define KSEG   (S_LEN / KSPLIT)  // 512

// fold softmax scale into Q at projection time: 1/sqrt(64) * log2(e)
#define QSCALE 0.18033688011112042f

typedef unsigned short u16;
typedef short     bf16x8 __attribute__((ext_vector_type(8)));
typedef _Float16  f16x8  __attribute__((ext_vector_type(8)));
typedef __fp16    h16x2  __attribute__((ext_vector_type(2)));   // cvt_pkrtz return type
typedef float     f32x4  __attribute__((ext_vector_type(4)));

__device__ __forceinline__ u16 f2bf(float f) {
    union { float f; unsigned u; } v; v.f = f;
    unsigned r = v.u + 0x7fffu + ((v.u >> 16) & 1u);   // RNE
    return (u16)(r >> 16);
}
__device__ __forceinline__ float bf2f(u16 h) {
    union { unsigned u; float f; } v; v.u = ((unsigned)h) << 16;
    return v.f;
}

// async global->LDS DMA, 16 B per lane (global_load_lds_dwordx4).
__device__ __forceinline__ void load_lds16(const u16* g, u16* l) {
    __builtin_amdgcn_global_load_lds(
        (const __attribute__((address_space(1))) unsigned int*)g,
        (__attribute__((address_space(3))) unsigned int*)l, 16, 0, 0);
}

// ---------------------------------------------------------------------------
// fp32 -> bf16 bulk convert (n % 4 == 0)
// ---------------------------------------------------------------------------
__global__ void cvt_bf16(const float* __restrict__ in, u16* __restrict__ out, int n)
{
    int i = (blockIdx.x * 256 + threadIdx.x) * 4;
    if (i + 3 < n) {
        float4 v = *(const float4*)(in + i);
        u16 o[4] = { f2bf(v.x), f2bf(v.y), f2bf(v.z), f2bf(v.w) };
        *(uint2*)(out + i) = *(const uint2*)o;
    }
}

// three QKV weight matrices -> concat bf16 buffer, one launch (grid.y = seg)
__global__ void cvt_w3(const float* __restrict__ Wq, const float* __restrict__ Wk,
                       const float* __restrict__ Wv, u16* __restrict__ out)
{
    const int seg = blockIdx.y;
    const float* src = (seg == 0) ? Wq : (seg == 1) ? Wk : Wv;
    int i = (blockIdx.x * 256 + threadIdx.x) * 4;
    float4 v = *(const float4*)(src + i);
    u16 o[4] = { f2bf(v.x), f2bf(v.y), f2bf(v.z), f2bf(v.w) };
    *(uint2*)(out + (size_t)seg * E_DIM * E_DIM + i) = *(const uint2*)o;
}

// ---------------------------------------------------------------------------
// ctx = a + b + c + d  (bf16 in, fp32 add, bf16 out).  In-place on a is safe.
// ---------------------------------------------------------------------------
__global__ void combine_ctx4(const u16* __restrict__ a, const u16* __restrict__ b,
                             const u16* __restrict__ c, const u16* __restrict__ d,
                             u16* __restrict__ o, int n)
{
    int i = (blockIdx.x * 256 + threadIdx.x) * 4;
    if (i + 3 < n) {
        uint2 ua = *(const uint2*)(a + i);
        uint2 ub = *(const uint2*)(b + i);
        uint2 uc = *(const uint2*)(c + i);
        uint2 ud = *(const uint2*)(d + i);
        const u16* pa = (const u16*)&ua; const u16* pb = (const u16*)&ub;
        const u16* pc = (const u16*)&uc; const u16* pd = (const u16*)&ud;
        u16 ov[4];
#pragma unroll
        for (int j = 0; j < 4; ++j)
            ov[j] = f2bf(bf2f(pa[j]) + bf2f(pb[j]) + bf2f(pc[j]) + bf2f(pd[j]));
        *(uint2*)(o + i) = *(const uint2*)ov;
    }
}

// ---------------------------------------------------------------------------
// Fused QKV projection GEMM (m97-style DMA staging).
//   seg 0 -> Q, bf16, PRE-SCALED by QSCALE (softmax scale folded in)
//   seg 1 -> K, bf16
//   seg 2 -> V, written TRANSPOSED Vt[b][e][s] in FP16 (PV runs fp16 MFMA)
// ---------------------------------------------------------------------------
__global__ __launch_bounds__(256)
void gemm_qkv(const u16* __restrict__ A, const u16* __restrict__ W3,
              const float* __restrict__ bq, const float* __restrict__ bk,
              const float* __restrict__ bv,
              u16* __restrict__ Qb, u16* __restrict__ Kb, u16* __restrict__ Vtb)
{
    __shared__ u16 Al[128 * 32];
    __shared__ u16 Bl[128 * 32];
    const int K = E_DIM;
    const int t = threadIdx.x;
    const int w = t >> 6, lane = t & 63;
    const int quad = lane >> 4, lm = lane & 15;
    const int wy = w >> 1, wx = w & 1;
    const int m0 = blockIdx.x * 128, n0 = blockIdx.y * 128;
    const int lrow  = lane >> 2;
    const int lcol8 = (lane & 3) * 8;

    f32x4 acc[4][4] = {};

    for (int kb = 0; kb < K; kb += 32) {
        __syncthreads();
#pragma unroll
        for (int i = 0; i < 2; ++i) {
            const int r0 = w * 32 + i * 16;
            load_lds16(A  + (size_t)(m0 + r0 + lrow) * K + kb + lcol8, &Al[r0 * 32]);
            load_lds16(W3 + (size_t)(n0 + r0 + lrow) * K + kb + lcol8, &Bl[r0 * 32]);
        }
        __syncthreads();

        bf16x8 af[4], bfr[4];
#pragma unroll
        for (int i = 0; i < 4; ++i)
            af[i] = *(const bf16x8*)(Al + (wy * 64 + i * 16 + lm) * 32 + quad * 8);
#pragma unroll
        for (int j = 0; j < 4; ++j)
            bfr[j] = *(const bf16x8*)(Bl + (wx * 64 + j * 16 + lm) * 32 + quad * 8);
#pragma unroll
        for (int i = 0; i < 4; ++i)
#pragma unroll
            for (int j = 0; j < 4; ++j)
                acc[i][j] = __builtin_amdgcn_mfma_f32_16x16x32_bf16(af[i], bfr[j], acc[i][j], 0, 0, 0);
    }

    const int seg = n0 >> 10;            // 0=Q, 1=K, 2=V
    const int nl0 = n0 & 1023;
    const float* bs = (seg == 0) ? bq : (seg == 1) ? bk : bv;

    if (seg < 2) {
        u16* dst = (seg == 0) ? Qb : Kb;
        const float scl = (seg == 0) ? QSCALE : 1.0f;
#pragma unroll
        for (int j = 0; j < 4; ++j) {
            const int n = nl0 + wx * 64 + j * 16 + lm;
            const float bias = bs[n];
#pragma unroll
            for (int i = 0; i < 4; ++i) {
                const int mrow = m0 + wy * 64 + i * 16 + quad * 4;
#pragma unroll
                for (int rg = 0; rg < 4; ++rg)
                    dst[(size_t)(mrow + rg) * E_DIM + n] = f2bf((acc[i][j][rg] + bias) * scl);
            }
        }
    } else {
        // V: fp16, transposed -> Vt[b][e][s]
#pragma unroll
        for (int j = 0; j < 4; ++j) {
            const int n = nl0 + wx * 64 + j * 16 + lm;
            const float bias = bs[n];
#pragma unroll
            for (int i = 0; i < 4; ++i) {
                const int mrow = m0 + wy * 64 + i * 16 + quad * 4;
                const int batch = mrow >> 11;
                const int sloc  = mrow & 2047;
                u16 o[4];
#pragma unroll
                for (int rg = 0; rg < 4; ++rg) {
                    union { _Float16 h; u16 u; } cv;
                    cv.h = (_Float16)(acc[i][j][rg] + bias);
                    o[rg] = cv.u;
                }
                *(uint2*)&Vtb[(size_t)batch * E_DIM * S_LEN + (size_t)n * S_LEN + sloc]
                    = *(const uint2*)o;
            }
        }
    }
}

// ---------------------------------------------------------------------------
// Output projection GEMM — unchanged.
// ---------------------------------------------------------------------------
__global__ __launch_bounds__(256)
void gemm_wo(const u16* __restrict__ A, const u16* __restrict__ B,
             const float* __restrict__ bias, float* __restrict__ C)
{
    __shared__ u16 Al[128 * 32];
    __shared__ u16 Bl[128 * 32];
    const int K = E_DIM, N = E_DIM;
    const int t = threadIdx.x;
    const int w = t >> 6, lane = t & 63;
    const int quad = lane >> 4, lm = lane & 15;
    const int wy = w >> 1, wx = w & 1;
    const int m0 = blockIdx.x * 128, n0 = blockIdx.y * 128;
    const int lrow  = lane >> 2;
    const int lcol8 = (lane & 3) * 8;

    f32x4 acc[4][4] = {};

    for (int kb = 0; kb < K; kb += 32) {
        __syncthreads();
#pragma unroll
        for (int i = 0; i < 2; ++i) {
            const int r0 = w * 32 + i * 16;
            load_lds16(A + (size_t)(m0 + r0 + lrow) * K + kb + lcol8, &Al[r0 * 32]);
            load_lds16(B + (size_t)(n0 + r0 + lrow) * K + kb + lcol8, &Bl[r0 * 32]);
        }
        __syncthreads();

        bf16x8 af[4], bfr[4];
#pragma unroll
        for (int i = 0; i < 4; ++i)
            af[i] = *(const bf16x8*)(Al + (wy * 64 + i * 16 + lm) * 32 + quad * 8);
#pragma unroll
        for (int j = 0; j < 4; ++j)
            bfr[j] = *(const bf16x8*)(Bl + (wx * 64 + j * 16 + lm) * 32 + quad * 8);
#pragma unroll
        for (int i = 0; i < 4; ++i)
#pragma unroll
            for (int j = 0; j < 4; ++j)
                acc[i][j] = __builtin_amdgcn_mfma_f32_16x16x32_bf16(af[i], bfr[j], acc[i][j], 0, 0, 0);
    }

#pragma unroll
    for (int j = 0; j < 4; ++j) {
        const int n = n0 + wx * 64 + j * 16 + lm;
        const float bs = bias[n];
#pragma unroll
        for (int i = 0; i < 4; ++i) {
            const int mrow = m0 + wy * 64 + i * 16 + quad * 4;
#pragma unroll
            for (int rg = 0; rg < 4; ++rg)
                C[(size_t)(mrow + rg) * N + n] = acc[i][j][rg] + bs;
        }
    }
}

// ---------------------------------------------------------------------------
// attn_v9 = v7 body with fp16 S-exchange, KSPLIT=4, combo->XCD pinning,
// 4 blocks/CU (launch_bounds(256,4), LDS 36.9 KB, VGPR cap 128).
//   S4h [512 slots][16 halves]: wave w writes its 4 heads (2 cvt_pkrtz ->
//     b64) at half-offset w*4; heads land IN ORDER, so softmax reads the
//     16-head vector as 2 contiguous b128 and unpacks fp16->f32.
//   Everything else byte-identical to v7 (P5 layout, barriers, PV).
// ---------------------------------------------------------------------------
__global__ __launch_bounds__(256, 4)
void attn_v9(const u16* __restrict__ Q, const u16* __restrict__ K,
             const u16* __restrict__ Vt,
             u16* __restrict__ c0, u16* __restrict__ c1,
             u16* __restrict__ c2, u16* __restrict__ c3)
{
    __shared__ __align__(16) u16 smem[18432];   // 36864 B
    u16* S4h = smem;                 // [512][16] fp16 halves = 16384 B
    u16* P5  = smem + 8192;          // [16h][16q][40] halves = 20480 B

    const int t     = threadIdx.x;
    const int w     = t >> 6, lane = t & 63;
    const int quad  = lane >> 4, lm = lane & 15;

    // combo->XCD pinning (model: XCD = blockIdx % 8): 8 combos (b,kq), one
    // per XCD; each combo's K-quarter (1MB) + V-quarter (1MB) is L2-resident.
    // Pure permutation — correctness independent of the mapping.
    const int i     = blockIdx.x;       // 0..1023
    const int combo = i & 7;
    const int b     = combo >> 2;
    const int kq    = combo & 3;
    const int qt    = i >> 3;           // 0..127
    const int q0    = qt * 16;

    const size_t qbase = ((size_t)b * S_LEN + q0) * E_DIM;
    const size_t kmat  = (size_t)b * S_LEN * E_DIM;
    const size_t vtb   = (size_t)b * E_DIM * S_LEN;

    // Q fragments (B-operand of swapped QK^T), loop-invariant
    bf16x8 qf[4][2];
#pragma unroll
    for (int h2 = 0; h2 < 4; ++h2)
#pragma unroll
        for (int hf = 0; hf < 2; ++hf)
            qf[h2][hf] = *(const bf16x8*)(Q + qbase + (size_t)lm * E_DIM
                                          + (w * 4 + h2) * 64 + hf * 32 + quad * 8);

    f32x4 oacc[4][4] = {};   // [h2][dtile]
    const int kbeg = kq * KSEG;
    const int sq = t & 15, sj = t >> 4;   // softmax slot: q=sq, k in {2sj, 2sj+1}

    for (int c = 0; c < KSEG / 32; ++c) {   // 16 chunks
        const int k0 = kbeg + c * 32;

        // ---- swapped QK^T: S[k][q] for this wave's 4 heads ----
        f32x4 sacc[4][2];
#pragma unroll
        for (int h2 = 0; h2 < 4; ++h2) {
            const int h = w * 4 + h2;
#pragma unroll
            for (int kt = 0; kt < 2; ++kt) {
                f32x4 sf = {};
#pragma unroll
                for (int hf = 0; hf < 2; ++hf) {
                    bf16x8 kf = *(const bf16x8*)(K + kmat
                                 + (size_t)(k0 + kt * 16 + lm) * E_DIM
                                 + h * 64 + hf * 32 + quad * 8);
                    sf = __builtin_amdgcn_mfma_f32_16x16x32_bf16(kf, qf[h2][hf], sf, 0, 0, 0);
                }
                sacc[h2][kt] = sf;
            }
        }

        // ---- pack 4 heads per (k,q) slot -> fp16, one b64 store each ----
        // (no barrier needed: all waves' S4h reads retired at prev B3)
#pragma unroll
        for (int kt = 0; kt < 2; ++kt)
#pragma unroll
            for (int rg = 0; rg < 4; ++rg) {
                union { h16x2 v; unsigned u; } p0, p1;
                p0.v = __builtin_amdgcn_cvt_pkrtz(sacc[0][kt][rg], sacc[1][kt][rg]);
                p1.v = __builtin_amdgcn_cvt_pkrtz(sacc[2][kt][rg], sacc[3][kt][rg]);
                uint2 pk; pk.x = p0.u; pk.y = p1.u;
                const int kl = kt * 16 + quad * 4 + rg;
                *(uint2*)(S4h + (size_t)(kl * 16 + lm) * 16 + w * 4) = pk;
            }

        // V prefetch into regs; latency hides under softmax (vmcnt never drained)
        f16x8 vf[4][4];
#pragma unroll
        for (int h2 = 0; h2 < 4; ++h2)
#pragma unroll
            for (int dt = 0; dt < 4; ++dt)
                vf[h2][dt] = *(const f16x8*)(Vt + vtb
                             + (size_t)((w * 4 + h2) * 64 + dt * 16 + lm) * S_LEN
                             + k0 + quad * 8);

        asm volatile("s_waitcnt lgkmcnt(0)" ::: "memory");
        __builtin_amdgcn_s_barrier();   // B2: S4h visible everywhere

        // ---- register softmax over heads: 2 (k,q) slots per thread ----
        float pv[2][16];
#pragma unroll
        for (int ks = 0; ks < 2; ++ks) {
            const u16* base = S4h + (size_t)((2 * sj + ks) * 16 + sq) * 16;
            union { uint4 u; __fp16 h[8]; } r0, r1;
            r0.u = *(const uint4*)(base);
            r1.u = *(const uint4*)(base + 8);
            float s[16];
#pragma unroll
            for (int z = 0; z < 8; ++z) {
                s[z]     = (float)r0.h[z];
                s[8 + z] = (float)r1.h[z];
            }
            float m = s[0];
#pragma unroll
            for (int h = 1; h < 16; ++h) m = fmaxf(m, s[h]);
            float sum = 0.f;
#pragma unroll
            for (int h = 0; h < 16; ++h) {
                const float e = __builtin_amdgcn_exp2f(s[h] - m);  // scale folded into Q
                pv[ks][h] = e; sum += e;
            }
            const float inv = __builtin_amdgcn_rcpf(sum);
#pragma unroll
            for (int h = 0; h < 16; ++h) pv[ks][h] *= inv;
        }
        // pack fp16 pairs (k=2sj, 2sj+1) -> one u32 store per head
#pragma unroll
        for (int h = 0; h < 16; ++h) {
            union { h16x2 v; unsigned u; } cv;
            cv.v = __builtin_amdgcn_cvt_pkrtz(pv[0][h], pv[1][h]);
            *(unsigned*)(P5 + (size_t)h * 640 + sq * 40 + 2 * sj) = cv.u;
        }

        asm volatile("s_waitcnt lgkmcnt(0)" ::: "memory");
        __builtin_amdgcn_s_barrier();   // B3: P5 visible; all S4h/P5 reads retired

        // ---- PV: fp16 MFMA, P A-frag one b128 per head, V from regs ----
#pragma unroll
        for (int h2 = 0; h2 < 4; ++h2) {
            f16x8 pa = *(const f16x8*)(P5 + (size_t)(w * 4 + h2) * 640
                                       + lm * 40 + quad * 8);
#pragma unroll
            for (int dt = 0; dt < 4; ++dt)
                oacc[h2][dt] = __builtin_amdgcn_mfma_f32_16x16x32_f16(pa, vf[h2][dt],
                                                                      oacc[h2][dt], 0, 0, 0);
        }
    }

    __syncthreads();
    u16* Ol = smem;          // [16 q][1024 e] = 32768 B <= 36864 B
#pragma unroll
    for (int h2 = 0; h2 < 4; ++h2) {
        const int h = w * 4 + h2;
#pragma unroll
        for (int dt = 0; dt < 4; ++dt)
#pragma unroll
            for (int rg = 0; rg < 4; ++rg)
                Ol[(quad * 4 + rg) * 1024 + h * 64 + dt * 16 + lm] = f2bf(oacc[h2][dt][rg]);
    }
    __syncthreads();
    u16* dst = (kq == 0) ? c0 : (kq == 1) ? c1 : (kq == 2) ? c2 : c3;
#pragma unroll
    for (int i2 = 0; i2 < 8; ++i2) {
        const int unit = i2 * 256 + t;
        const int r = unit >> 7, cu = unit & 127;
        *(bf16x8*)(dst + ((size_t)b * S_LEN + q0 + r) * E_DIM + cu * 8) =
            *(const bf16x8*)(Ol + r * 1024 + cu * 8);
    }
}

// ---------------------------------------------------------------------------
// Workspace overlay plan (56 MB total):
//   [xb 4M][W3 3M][Wob 1M][Qb 4M][Kb 4M][Vtb 4M][ctxA 4M][ctxB 4M]  (u16)
//   ctxC := xb    (dead after gemm_qkv)
//   ctxD := W3    (spans W3+Wob; Wo cvt DEFERRED until after combine)
// ---------------------------------------------------------------------------
extern "C" void kernel_launch(void* const* d_in, const int* in_sizes, int n_in,
                              void* d_out, int out_size, void* d_ws, size_t ws_size,
                              hipStream_t stream)
{
    const float* x  = (const float*)d_in[0];
    const float* Wq = (const float*)d_in[1];
    const float* bq = (const float*)d_in[2];
    const float* Wk = (const float*)d_in[3];
    const float* bk = (const float*)d_in[4];
    const float* Wv = (const float*)d_in[5];
    const float* bv = (const float*)d_in[6];
    const float* Wo = (const float*)d_in[7];
    const float* bo = (const float*)d_in[8];
    float* out = (float*)d_out;

    const size_t MAT = (size_t)M_ROWS * E_DIM;   // 4M elems
    const size_t WSZ = (size_t)E_DIM * E_DIM;    // 1M elems
    u16* xb   = (u16*)d_ws;
    u16* W3   = xb   + MAT;
    u16* Wob  = W3   + 3 * WSZ;
    u16* Qb   = Wob  + WSZ;
    u16* Kb   = Qb   + MAT;
    u16* Vtb  = Kb   + MAT;          // V transposed [b][e][s], FP16
    u16* ctxA = Vtb  + MAT;
    u16* ctxB = ctxA + MAT;
    u16* ctxC = xb;                  // overlay (dead after gemm_qkv)
    u16* ctxD = W3;                  // overlay (W3+Wob dead during attn)

    // 1) convert x + QKV weights to bf16 (Wo deferred; 2 launches not 5)
    cvt_bf16<<<(int)(MAT / 1024), 256, 0, stream>>>(x, xb, (int)MAT);
    dim3 wgrid(WSZ / 1024, 3);
    cvt_w3<<<wgrid, 256, 0, stream>>>(Wq, Wk, Wv, W3);

    // 2) fused QKV projection (Q pre-scaled, V fp16-transposed)
    dim3 qkvgrid(M_ROWS / 128, 3 * E_DIM / 128);   // 32 x 24 = 768 blocks
    gemm_qkv<<<qkvgrid, 256, 0, stream>>>(xb, W3, bq, bk, bv, Qb, Kb, Vtb);

    // 3) fused MFMA attention, KSPLIT=4, combo->XCD pinned, 4 blocks/CU
    attn_v9<<<BATCH * 128 * KSPLIT, 256, 0, stream>>>(Qb, Kb, Vtb,
                                                      ctxA, ctxB, ctxC, ctxD);

    // 4) combine k-quarters (in place into ctxA)
    combine_ctx4<<<(int)(MAT / 1024), 256, 0, stream>>>(ctxA, ctxB, ctxC, ctxD,
                                                        ctxA, (int)MAT);

    // 5) Wo -> bf16 (deferred: its region doubled as ctxD during attn)
    cvt_bf16<<<(int)(WSZ / 1024), 256, 0, stream>>>(Wo, Wob, (int)WSZ);

    // 6) output projection (fp32 out)
    dim3 ogrid(M_ROWS / 128, E_DIM / 128);         // 32 x 8
    gemm_wo<<<ogrid, 256, 0, stream>>>(ctxA, Wob, bo, out);
}

// Round 8
// 428.395 us; speedup vs baseline: 1.4043x; 1.4043x over previous
//
#include <hip/hip_runtime.h>
#include <cstddef>
#include <cstdint>

// Problem: B=2, S=2048, E=1024, H=16, D=64.  Softmax over HEADS (ref quirk).
#define BATCH 2
#define S_LEN 2048
#define E_DIM 1024
#define NH    16
#define HD    64
#define M_ROWS (BATCH * S_LEN)   // 4096
#define KSPLIT 4
#define KSEG   (S_LEN / KSPLIT)  // 512

// fold softmax scale into Q at projection time: 1/sqrt(64) * log2(e)
#define QSCALE 0.18033688011112042f

typedef unsigned short u16;
typedef short     bf16x8 __attribute__((ext_vector_type(8)));
typedef _Float16  f16x8  __attribute__((ext_vector_type(8)));
typedef __fp16    h16x2  __attribute__((ext_vector_type(2)));   // cvt_pkrtz return type
typedef float     f32x4  __attribute__((ext_vector_type(4)));

__device__ __forceinline__ u16 f2bf(float f) {
    union { float f; unsigned u; } v; v.f = f;
    unsigned r = v.u + 0x7fffu + ((v.u >> 16) & 1u);   // RNE
    return (u16)(r >> 16);
}
__device__ __forceinline__ float bf2f(u16 h) {
    union { unsigned u; float f; } v; v.u = ((unsigned)h) << 16;
    return v.f;
}

// async global->LDS DMA, 16 B per lane (global_load_lds_dwordx4).
__device__ __forceinline__ void load_lds16(const u16* g, u16* l) {
    __builtin_amdgcn_global_load_lds(
        (const __attribute__((address_space(1))) unsigned int*)g,
        (__attribute__((address_space(3))) unsigned int*)l, 16, 0, 0);
}

// ---------------------------------------------------------------------------
// fp32 -> bf16 bulk convert (n % 4 == 0)
// ---------------------------------------------------------------------------
__global__ void cvt_bf16(const float* __restrict__ in, u16* __restrict__ out, int n)
{
    int i = (blockIdx.x * 256 + threadIdx.x) * 4;
    if (i + 3 < n) {
        float4 v = *(const float4*)(in + i);
        u16 o[4] = { f2bf(v.x), f2bf(v.y), f2bf(v.z), f2bf(v.w) };
        *(uint2*)(out + i) = *(const uint2*)o;
    }
}

// three QKV weight matrices -> concat bf16 buffer, one launch (grid.y = seg)
__global__ void cvt_w3(const float* __restrict__ Wq, const float* __restrict__ Wk,
                       const float* __restrict__ Wv, u16* __restrict__ out)
{
    const int seg = blockIdx.y;
    const float* src = (seg == 0) ? Wq : (seg == 1) ? Wk : Wv;
    int i = (blockIdx.x * 256 + threadIdx.x) * 4;
    float4 v = *(const float4*)(src + i);
    u16 o[4] = { f2bf(v.x), f2bf(v.y), f2bf(v.z), f2bf(v.w) };
    *(uint2*)(out + (size_t)seg * E_DIM * E_DIM + i) = *(const uint2*)o;
}

// ---------------------------------------------------------------------------
// ctx = a + b + c + d  (bf16 in, fp32 add, bf16 out).  In-place on a is safe.
// ---------------------------------------------------------------------------
__global__ void combine_ctx4(const u16* __restrict__ a, const u16* __restrict__ b,
                             const u16* __restrict__ c, const u16* __restrict__ d,
                             u16* __restrict__ o, int n)
{
    int i = (blockIdx.x * 256 + threadIdx.x) * 4;
    if (i + 3 < n) {
        uint2 ua = *(const uint2*)(a + i);
        uint2 ub = *(const uint2*)(b + i);
        uint2 uc = *(const uint2*)(c + i);
        uint2 ud = *(const uint2*)(d + i);
        const u16* pa = (const u16*)&ua; const u16* pb = (const u16*)&ub;
        const u16* pc = (const u16*)&uc; const u16* pd = (const u16*)&ud;
        u16 ov[4];
#pragma unroll
        for (int j = 0; j < 4; ++j)
            ov[j] = f2bf(bf2f(pa[j]) + bf2f(pb[j]) + bf2f(pc[j]) + bf2f(pd[j]));
        *(uint2*)(o + i) = *(const uint2*)ov;
    }
}

// ---------------------------------------------------------------------------
// Fused QKV projection GEMM (m97-style DMA staging).
//   seg 0 -> Q, bf16, PRE-SCALED by QSCALE (softmax scale folded in)
//   seg 1 -> K, bf16
//   seg 2 -> V, written TRANSPOSED Vt[b][e][s] in FP16 (PV runs fp16 MFMA)
// ---------------------------------------------------------------------------
__global__ __launch_bounds__(256)
void gemm_qkv(const u16* __restrict__ A, const u16* __restrict__ W3,
              const float* __restrict__ bq, const float* __restrict__ bk,
              const float* __restrict__ bv,
              u16* __restrict__ Qb, u16* __restrict__ Kb, u16* __restrict__ Vtb)
{
    __shared__ u16 Al[128 * 32];
    __shared__ u16 Bl[128 * 32];
    const int K = E_DIM;
    const int t = threadIdx.x;
    const int w = t >> 6, lane = t & 63;
    const int quad = lane >> 4, lm = lane & 15;
    const int wy = w >> 1, wx = w & 1;
    const int m0 = blockIdx.x * 128, n0 = blockIdx.y * 128;
    const int lrow  = lane >> 2;
    const int lcol8 = (lane & 3) * 8;

    f32x4 acc[4][4] = {};

    for (int kb = 0; kb < K; kb += 32) {
        __syncthreads();
#pragma unroll
        for (int i = 0; i < 2; ++i) {
            const int r0 = w * 32 + i * 16;
            load_lds16(A  + (size_t)(m0 + r0 + lrow) * K + kb + lcol8, &Al[r0 * 32]);
            load_lds16(W3 + (size_t)(n0 + r0 + lrow) * K + kb + lcol8, &Bl[r0 * 32]);
        }
        __syncthreads();

        bf16x8 af[4], bfr[4];
#pragma unroll
        for (int i = 0; i < 4; ++i)
            af[i] = *(const bf16x8*)(Al + (wy * 64 + i * 16 + lm) * 32 + quad * 8);
#pragma unroll
        for (int j = 0; j < 4; ++j)
            bfr[j] = *(const bf16x8*)(Bl + (wx * 64 + j * 16 + lm) * 32 + quad * 8);
#pragma unroll
        for (int i = 0; i < 4; ++i)
#pragma unroll
            for (int j = 0; j < 4; ++j)
                acc[i][j] = __builtin_amdgcn_mfma_f32_16x16x32_bf16(af[i], bfr[j], acc[i][j], 0, 0, 0);
    }

    const int seg = n0 >> 10;            // 0=Q, 1=K, 2=V
    const int nl0 = n0 & 1023;
    const float* bs = (seg == 0) ? bq : (seg == 1) ? bk : bv;

    if (seg < 2) {
        u16* dst = (seg == 0) ? Qb : Kb;
        const float scl = (seg == 0) ? QSCALE : 1.0f;
#pragma unroll
        for (int j = 0; j < 4; ++j) {
            const int n = nl0 + wx * 64 + j * 16 + lm;
            const float bias = bs[n];
#pragma unroll
            for (int i = 0; i < 4; ++i) {
                const int mrow = m0 + wy * 64 + i * 16 + quad * 4;
#pragma unroll
                for (int rg = 0; rg < 4; ++rg)
                    dst[(size_t)(mrow + rg) * E_DIM + n] = f2bf((acc[i][j][rg] + bias) * scl);
            }
        }
    } else {
        // V: fp16, transposed -> Vt[b][e][s]
#pragma unroll
        for (int j = 0; j < 4; ++j) {
            const int n = nl0 + wx * 64 + j * 16 + lm;
            const float bias = bs[n];
#pragma unroll
            for (int i = 0; i < 4; ++i) {
                const int mrow = m0 + wy * 64 + i * 16 + quad * 4;
                const int batch = mrow >> 11;
                const int sloc  = mrow & 2047;
                u16 o[4];
#pragma unroll
                for (int rg = 0; rg < 4; ++rg) {
                    union { _Float16 h; u16 u; } cv;
                    cv.h = (_Float16)(acc[i][j][rg] + bias);
                    o[rg] = cv.u;
                }
                *(uint2*)&Vtb[(size_t)batch * E_DIM * S_LEN + (size_t)n * S_LEN + sloc]
                    = *(const uint2*)o;
            }
        }
    }
}

// ---------------------------------------------------------------------------
// Output projection GEMM — unchanged.
// ---------------------------------------------------------------------------
__global__ __launch_bounds__(256)
void gemm_wo(const u16* __restrict__ A, const u16* __restrict__ B,
             const float* __restrict__ bias, float* __restrict__ C)
{
    __shared__ u16 Al[128 * 32];
    __shared__ u16 Bl[128 * 32];
    const int K = E_DIM, N = E_DIM;
    const int t = threadIdx.x;
    const int w = t >> 6, lane = t & 63;
    const int quad = lane >> 4, lm = lane & 15;
    const int wy = w >> 1, wx = w & 1;
    const int m0 = blockIdx.x * 128, n0 = blockIdx.y * 128;
    const int lrow  = lane >> 2;
    const int lcol8 = (lane & 3) * 8;

    f32x4 acc[4][4] = {};

    for (int kb = 0; kb < K; kb += 32) {
        __syncthreads();
#pragma unroll
        for (int i = 0; i < 2; ++i) {
            const int r0 = w * 32 + i * 16;
            load_lds16(A + (size_t)(m0 + r0 + lrow) * K + kb + lcol8, &Al[r0 * 32]);
            load_lds16(B + (size_t)(n0 + r0 + lrow) * K + kb + lcol8, &Bl[r0 * 32]);
        }
        __syncthreads();

        bf16x8 af[4], bfr[4];
#pragma unroll
        for (int i = 0; i < 4; ++i)
            af[i] = *(const bf16x8*)(Al + (wy * 64 + i * 16 + lm) * 32 + quad * 8);
#pragma unroll
        for (int j = 0; j < 4; ++j)
            bfr[j] = *(const bf16x8*)(Bl + (wx * 64 + j * 16 + lm) * 32 + quad * 8);
#pragma unroll
        for (int i = 0; i < 4; ++i)
#pragma unroll
            for (int j = 0; j < 4; ++j)
                acc[i][j] = __builtin_amdgcn_mfma_f32_16x16x32_bf16(af[i], bfr[j], acc[i][j], 0, 0, 0);
    }

#pragma unroll
    for (int j = 0; j < 4; ++j) {
        const int n = n0 + wx * 64 + j * 16 + lm;
        const float bs = bias[n];
#pragma unroll
        for (int i = 0; i < 4; ++i) {
            const int mrow = m0 + wy * 64 + i * 16 + quad * 4;
#pragma unroll
            for (int rg = 0; rg < 4; ++rg)
                C[(size_t)(mrow + rg) * N + n] = acc[i][j][rg] + bs;
        }
    }
}

// ---------------------------------------------------------------------------
// attn_v10 = v9 body with __launch_bounds__(256, 2).
// R7 showed (256,4) makes the allocator cap at 64 arch-VGPRs -> 1.5 GB
// scratch spill.  (256,2) is the proven no-spill codegen (116 VGPR in
// v5/v7); since 116 <= 128 the HW can still host 4 waves/SIMD, and LDS
// 38912 B x 4 = 152 KB < 160 KB allows 4 blocks/CU -> grid 1024 fully
// resident WITHOUT any register cap.  S4h pitch 18 halves (36 B) spreads
// banks on both the b64 writes and the uint4 softmax reads.
// ---------------------------------------------------------------------------
__global__ __launch_bounds__(256, 2)
void attn_v10(const u16* __restrict__ Q, const u16* __restrict__ K,
              const u16* __restrict__ Vt,
              u16* __restrict__ c0, u16* __restrict__ c1,
              u16* __restrict__ c2, u16* __restrict__ c3)
{
    __shared__ __align__(16) u16 smem[19456];   // 38912 B
    u16* S4h = smem;                 // [512 slots][18] fp16 halves = 18432 B
    u16* P5  = smem + 9216;          // [16h][16q][40] halves      = 20480 B

    const int t     = threadIdx.x;
    const int w     = t >> 6, lane = t & 63;
    const int quad  = lane >> 4, lm = lane & 15;

    // combo->XCD pinning (model: XCD = blockIdx % 8): 8 combos (b,kq), one
    // per XCD; each combo's K-quarter (1MB) + V-quarter (1MB) is L2-resident.
    const int i     = blockIdx.x;       // 0..1023
    const int combo = i & 7;
    const int b     = combo >> 2;
    const int kq    = combo & 3;
    const int qt    = i >> 3;           // 0..127
    const int q0    = qt * 16;

    const size_t qbase = ((size_t)b * S_LEN + q0) * E_DIM;
    const size_t kmat  = (size_t)b * S_LEN * E_DIM;
    const size_t vtb   = (size_t)b * E_DIM * S_LEN;

    // Q fragments (B-operand of swapped QK^T), loop-invariant
    bf16x8 qf[4][2];
#pragma unroll
    for (int h2 = 0; h2 < 4; ++h2)
#pragma unroll
        for (int hf = 0; hf < 2; ++hf)
            qf[h2][hf] = *(const bf16x8*)(Q + qbase + (size_t)lm * E_DIM
                                          + (w * 4 + h2) * 64 + hf * 32 + quad * 8);

    f32x4 oacc[4][4] = {};   // [h2][dtile]
    const int kbeg = kq * KSEG;
    const int sq = t & 15, sj = t >> 4;   // softmax slot: q=sq, k in {2sj, 2sj+1}

    for (int c = 0; c < KSEG / 32; ++c) {   // 16 chunks
        const int k0 = kbeg + c * 32;

        // ---- swapped QK^T: S[k][q] for this wave's 4 heads ----
        f32x4 sacc[4][2];
#pragma unroll
        for (int h2 = 0; h2 < 4; ++h2) {
            const int h = w * 4 + h2;
#pragma unroll
            for (int kt = 0; kt < 2; ++kt) {
                f32x4 sf = {};
#pragma unroll
                for (int hf = 0; hf < 2; ++hf) {
                    bf16x8 kf = *(const bf16x8*)(K + kmat
                                 + (size_t)(k0 + kt * 16 + lm) * E_DIM
                                 + h * 64 + hf * 32 + quad * 8);
                    sf = __builtin_amdgcn_mfma_f32_16x16x32_bf16(kf, qf[h2][hf], sf, 0, 0, 0);
                }
                sacc[h2][kt] = sf;
            }
        }

        // ---- pack 4 heads per (k,q) slot -> fp16, one b64 store each ----
        // (no barrier needed: all waves' S4h reads retired at prev B3)
#pragma unroll
        for (int kt = 0; kt < 2; ++kt)
#pragma unroll
            for (int rg = 0; rg < 4; ++rg) {
                union { h16x2 v; unsigned u; } p0, p1;
                p0.v = __builtin_amdgcn_cvt_pkrtz(sacc[0][kt][rg], sacc[1][kt][rg]);
                p1.v = __builtin_amdgcn_cvt_pkrtz(sacc[2][kt][rg], sacc[3][kt][rg]);
                uint2 pk; pk.x = p0.u; pk.y = p1.u;
                const int kl = kt * 16 + quad * 4 + rg;
                *(uint2*)(S4h + (size_t)(kl * 16 + lm) * 18 + w * 4) = pk;
            }

        // V prefetch into regs; latency hides under softmax (vmcnt never drained)
        f16x8 vf[4][4];
#pragma unroll
        for (int h2 = 0; h2 < 4; ++h2)
#pragma unroll
            for (int dt = 0; dt < 4; ++dt)
                vf[h2][dt] = *(const f16x8*)(Vt + vtb
                             + (size_t)((w * 4 + h2) * 64 + dt * 16 + lm) * S_LEN
                             + k0 + quad * 8);

        asm volatile("s_waitcnt lgkmcnt(0)" ::: "memory");
        __builtin_amdgcn_s_barrier();   // B2: S4h visible everywhere

        // ---- register softmax over heads: 2 (k,q) slots per thread ----
        float pv[2][16];
#pragma unroll
        for (int ks = 0; ks < 2; ++ks) {
            const u16* base = S4h + (size_t)((2 * sj + ks) * 16 + sq) * 18;
            union { uint4 u; __fp16 h[8]; } r0, r1;
            r0.u = *(const uint4*)(base);
            r1.u = *(const uint4*)(base + 8);
            float s[16];
#pragma unroll
            for (int z = 0; z < 8; ++z) {
                s[z]     = (float)r0.h[z];
                s[8 + z] = (float)r1.h[z];
            }
            float m = s[0];
#pragma unroll
            for (int h = 1; h < 16; ++h) m = fmaxf(m, s[h]);
            float sum = 0.f;
#pragma unroll
            for (int h = 0; h < 16; ++h) {
                const float e = __builtin_amdgcn_exp2f(s[h] - m);  // scale folded into Q
                pv[ks][h] = e; sum += e;
            }
            const float inv = __builtin_amdgcn_rcpf(sum);
#pragma unroll
            for (int h = 0; h < 16; ++h) pv[ks][h] *= inv;
        }
        // pack fp16 pairs (k=2sj, 2sj+1) -> one u32 store per head
#pragma unroll
        for (int h = 0; h < 16; ++h) {
            union { h16x2 v; unsigned u; } cv;
            cv.v = __builtin_amdgcn_cvt_pkrtz(pv[0][h], pv[1][h]);
            *(unsigned*)(P5 + (size_t)h * 640 + sq * 40 + 2 * sj) = cv.u;
        }

        asm volatile("s_waitcnt lgkmcnt(0)" ::: "memory");
        __builtin_amdgcn_s_barrier();   // B3: P5 visible; all S4h/P5 reads retired

        // ---- PV: fp16 MFMA, P A-frag one b128 per head, V from regs ----
#pragma unroll
        for (int h2 = 0; h2 < 4; ++h2) {
            f16x8 pa = *(const f16x8*)(P5 + (size_t)(w * 4 + h2) * 640
                                       + lm * 40 + quad * 8);
#pragma unroll
            for (int dt = 0; dt < 4; ++dt)
                oacc[h2][dt] = __builtin_amdgcn_mfma_f32_16x16x32_f16(pa, vf[h2][dt],
                                                                      oacc[h2][dt], 0, 0, 0);
        }
    }

    __syncthreads();
    u16* Ol = smem;          // [16 q][1024 e] = 16384 u16 <= 19456 u16
#pragma unroll
    for (int h2 = 0; h2 < 4; ++h2) {
        const int h = w * 4 + h2;
#pragma unroll
        for (int dt = 0; dt < 4; ++dt)
#pragma unroll
            for (int rg = 0; rg < 4; ++rg)
                Ol[(quad * 4 + rg) * 1024 + h * 64 + dt * 16 + lm] = f2bf(oacc[h2][dt][rg]);
    }
    __syncthreads();
    u16* dst = (kq == 0) ? c0 : (kq == 1) ? c1 : (kq == 2) ? c2 : c3;
#pragma unroll
    for (int i2 = 0; i2 < 8; ++i2) {
        const int unit = i2 * 256 + t;
        const int r = unit >> 7, cu = unit & 127;
        *(bf16x8*)(dst + ((size_t)b * S_LEN + q0 + r) * E_DIM + cu * 8) =
            *(const bf16x8*)(Ol + r * 1024 + cu * 8);
    }
}

// ---------------------------------------------------------------------------
// Workspace overlay plan (56 MB total):
//   [xb 4M][W3 3M][Wob 1M][Qb 4M][Kb 4M][Vtb 4M][ctxA 4M][ctxB 4M]  (u16)
//   ctxC := xb    (dead after gemm_qkv)
//   ctxD := W3    (spans W3+Wob; Wo cvt DEFERRED until after combine)
// ---------------------------------------------------------------------------
extern "C" void kernel_launch(void* const* d_in, const int* in_sizes, int n_in,
                              void* d_out, int out_size, void* d_ws, size_t ws_size,
                              hipStream_t stream)
{
    const float* x  = (const float*)d_in[0];
    const float* Wq = (const float*)d_in[1];
    const float* bq = (const float*)d_in[2];
    const float* Wk = (const float*)d_in[3];
    const float* bk = (const float*)d_in[4];
    const float* Wv = (const float*)d_in[5];
    const float* bv = (const float*)d_in[6];
    const float* Wo = (const float*)d_in[7];
    const float* bo = (const float*)d_in[8];
    float* out = (float*)d_out;

    const size_t MAT = (size_t)M_ROWS * E_DIM;   // 4M elems
    const size_t WSZ = (size_t)E_DIM * E_DIM;    // 1M elems
    u16* xb   = (u16*)d_ws;
    u16* W3   = xb   + MAT;
    u16* Wob  = W3   + 3 * WSZ;
    u16* Qb   = Wob  + WSZ;
    u16* Kb   = Qb   + MAT;
    u16* Vtb  = Kb   + MAT;          // V transposed [b][e][s], FP16
    u16* ctxA = Vtb  + MAT;
    u16* ctxB = ctxA + MAT;
    u16* ctxC = xb;                  // overlay (dead after gemm_qkv)
    u16* ctxD = W3;                  // overlay (W3+Wob dead during attn)

    // 1) convert x + QKV weights to bf16 (Wo deferred; 2 launches not 5)
    cvt_bf16<<<(int)(MAT / 1024), 256, 0, stream>>>(x, xb, (int)MAT);
    dim3 wgrid(WSZ / 1024, 3);
    cvt_w3<<<wgrid, 256, 0, stream>>>(Wq, Wk, Wv, W3);

    // 2) fused QKV projection (Q pre-scaled, V fp16-transposed)
    dim3 qkvgrid(M_ROWS / 128, 3 * E_DIM / 128);   // 32 x 24 = 768 blocks
    gemm_qkv<<<qkvgrid, 256, 0, stream>>>(xb, W3, bq, bk, bv, Qb, Kb, Vtb);

    // 3) fused MFMA attention, KSPLIT=4, combo->XCD pinned, 4 blocks/CU
    attn_v10<<<BATCH * 128 * KSPLIT, 256, 0, stream>>>(Qb, Kb, Vtb,
                                                       ctxA, ctxB, ctxC, ctxD);

    // 4) combine k-quarters (in place into ctxA)
    combine_ctx4<<<(int)(MAT / 1024), 256, 0, stream>>>(ctxA, ctxB, ctxC, ctxD,
                                                        ctxA, (int)MAT);

    // 5) Wo -> bf16 (deferred: its region doubled as ctxD during attn)
    cvt_bf16<<<(int)(WSZ / 1024), 256, 0, stream>>>(Wo, Wob, (int)WSZ);

    // 6) output projection (fp32 out)
    dim3 ogrid(M_ROWS / 128, E_DIM / 128);         // 32 x 8
    gemm_wo<<<ogrid, 256, 0, stream>>>(ctxA, Wob, bo, out);
}